// Round 2
// baseline (1832.446 us; speedup 1.0000x reference)
//
#include <hip/hip_runtime.h>

typedef unsigned short ushort_t;
typedef unsigned int uint32;

#define NTOK 4096
#define SEQ 2048
#define DDIM 768
#define HDIM 3072
#define NEXP 8
#define KKEEP 819
#define NT_MAX 264

// MODE: 0 = fp32 inputs/outputs, 1 = bf16 inputs/outputs. Internal math fp32.

__device__ __forceinline__ float bf2f(ushort_t u) {
  uint32 x = ((uint32)u) << 16;
  return __uint_as_float(x);
}
__device__ __forceinline__ float lo16(uint32 u) { return __uint_as_float(u << 16); }
__device__ __forceinline__ float hi16(uint32 u) { return __uint_as_float(u & 0xFFFF0000u); }
__device__ __forceinline__ ushort_t f2bf(float f) {
  uint32 x = __float_as_uint(f);
  uint32 r = (x + 0x7FFFu + ((x >> 16) & 1u)) >> 16;
  return (ushort_t)r;
}
template <int MODE>
__device__ __forceinline__ float ld(const void* p, size_t i) {
  if (MODE == 0) return ((const float*)p)[i];
  return bf2f(((const ushort_t*)p)[i]);
}
// i must be a multiple of 4 (aligned 4-element load)
template <int MODE>
__device__ __forceinline__ void ld4(const void* p, size_t i, float* o) {
  if (MODE == 0) {
    float4 v = *(const float4*)((const float*)p + i);
    o[0] = v.x; o[1] = v.y; o[2] = v.z; o[3] = v.w;
  } else {
    uint2 v = *(const uint2*)((const ushort_t*)p + i);
    o[0] = lo16(v.x); o[1] = hi16(v.x); o[2] = lo16(v.y); o[3] = hi16(v.y);
  }
}
template <int MODE>
__device__ __forceinline__ void st(void* p, size_t i, float v) {
  if (MODE == 0) ((float*)p)[i] = v;
  else ((ushort_t*)p)[i] = f2bf(v);
}
__device__ __forceinline__ float gelu_f(float u) {
  float u3 = u * u * u;
  return 0.5f * u * (1.f + tanhf(0.7978845608028654f * (u + 0.044715f * u3)));
}

// ---------------- dtype detector: bf16-packed vs fp32 ---------------------------
__global__ void k_detect(const uint32* __restrict__ xw, int* __restrict__ flag) {
  int tid = threadIdx.x;  // 64 threads
  int cnt = 0;
  for (int i = tid; i < 256; i += 64) {
    uint32 w = xw[i];
    uint32 e = (w >> 7) & 0xFFu;  // exponent field of low-half bf16
    if (e >= 118u && e <= 133u) cnt++;
  }
#pragma unroll
  for (int off = 32; off > 0; off >>= 1) cnt += __shfl_down(cnt, off, 64);
  if (tid == 0) flag[0] = (cnt >= 192) ? 1 : 0;
}

// ---------------- gate: logits/softmax top-1, mask score, v init ----------------
template <int MODE>
__global__ __launch_bounds__(256) void k_gate(
    const void* __restrict__ x, const void* __restrict__ Wg,
    const void* __restrict__ bg, const void* __restrict__ Wm,
    const void* __restrict__ bm, const void* __restrict__ bv,
    const int* __restrict__ flag, int* __restrict__ expert,
    float* __restrict__ topp, float* __restrict__ score, float* __restrict__ v) {
  if (flag[0] != MODE) return;
  int tid = threadIdx.x;
  int lane = tid & 63, w = tid >> 6;
  int t = blockIdx.x * 4 + w;  // grid 1024 -> t < 4096
  float g[8];
#pragma unroll
  for (int e = 0; e < 8; ++e) g[e] = 0.f;
  float sm = 0.f;
  for (int d = lane; d < DDIM; d += 64) {
    float xv = ld<MODE>(x, (size_t)t * DDIM + d);
    float wr[8];
    ld4<MODE>(Wg, (size_t)d * 8, wr);
    ld4<MODE>(Wg, (size_t)d * 8 + 4, wr + 4);
#pragma unroll
    for (int e = 0; e < 8; ++e) g[e] += xv * wr[e];
    sm += xv * ld<MODE>(Wm, d);
  }
#pragma unroll
  for (int e = 0; e < 8; ++e) {
#pragma unroll
    for (int off = 32; off > 0; off >>= 1) g[e] += __shfl_down(g[e], off, 64);
  }
#pragma unroll
  for (int off = 32; off > 0; off >>= 1) sm += __shfl_down(sm, off, 64);
  if (lane == 0) {
    float l[8];
#pragma unroll
    for (int e = 0; e < 8; ++e) l[e] = g[e] + ld<MODE>(bg, e);
    int am = 0;
    float mx = l[0];
#pragma unroll
    for (int e = 1; e < 8; ++e) {
      if (l[e] > mx) { mx = l[e]; am = e; }  // first max kept (jnp.argmax)
    }
    float s = 0.f;
#pragma unroll
    for (int e = 0; e < 8; ++e) s += expf(l[e] - mx);
    expert[t] = am;
    topp[t] = 1.f / s;  // exp(mx-mx)/sum
    float z = sm + ld<MODE>(bm, 0);
    score[t] = 1.f / (1.f + expf(-z));
    v[t] = ld<MODE>(bv, 0);  // init for ffn2 atomic accumulation
  }
}

// ---------------- top-K threshold via bitonic sort (one block per batch) --------
__global__ __launch_bounds__(256) void k_thr(const float* __restrict__ score,
                                             float* __restrict__ thr) {
  __shared__ float s[SEQ];
  int b = blockIdx.x, tid = threadIdx.x;
  for (int i = tid; i < SEQ; i += 256) s[i] = score[b * SEQ + i];
  __syncthreads();
  for (int k = 2; k <= SEQ; k <<= 1) {
    for (int j = k >> 1; j > 0; j >>= 1) {
      for (int i = tid; i < SEQ; i += 256) {
        int ixj = i ^ j;
        if (ixj > i) {
          float a = s[i], c = s[ixj];
          bool up = ((i & k) == 0);
          if ((a > c) == up) { s[i] = c; s[ixj] = a; }
        }
      }
      __syncthreads();
    }
  }
  if (tid == 0) thr[b] = s[SEQ - KKEEP];  // K-th largest (ascending idx 1229)
}

// ---------------- bucket tokens by expert + tile descriptors --------------------
__global__ __launch_bounds__(256) void k_bucket(const int* __restrict__ expert,
                                                int* __restrict__ meta,
                                                int* __restrict__ tiles,
                                                int* __restrict__ perm) {
  __shared__ int cnt[NEXP];
  __shared__ int off[NEXP];
  int tid = threadIdx.x;
  if (tid < NEXP) cnt[tid] = 0;
  __syncthreads();
  for (int t = tid; t < NTOK; t += 256) atomicAdd(&cnt[expert[t]], 1);
  __syncthreads();
  if (tid == 0) {
    int run = 0, nt = 0;
    for (int e = 0; e < NEXP; ++e) {
      off[e] = run;
      int c = cnt[e];
      for (int s = 0; s < c; s += 16) {
        int mv = min(16, c - s);
        tiles[nt++] = (e << 20) | (mv << 12) | (run + s);
      }
      run += c;
    }
    meta[0] = nt;
  }
  __syncthreads();
  for (int t = tid; t < NTOK; t += 256) {
    int e = expert[t];
    int p = atomicAdd(&off[e], 1);
    perm[p] = t;
  }
}

// ---------------- grouped FFN layer 1: h = gelu(x @ W1[e] + b1[e]) --------------
template <int MODE>
__global__ __launch_bounds__(256) void k_ffn1(
    const void* __restrict__ x, const void* __restrict__ W1,
    const void* __restrict__ b1, const int* __restrict__ flag,
    const int* __restrict__ meta, const int* __restrict__ tiles,
    const int* __restrict__ perm, ushort_t* __restrict__ h) {
  if (flag[0] != MODE) return;
  __shared__ float xs[16 * DDIM];
  __shared__ int toks[16];
  if (blockIdx.x >= meta[0]) return;
  int desc = tiles[blockIdx.x];
  int e = desc >> 20, mv = (desc >> 12) & 31, start = desc & 0xFFF;
  int tid = threadIdx.x;
  if (tid < 16) toks[tid] = perm[start + ((tid < mv) ? tid : 0)];
  __syncthreads();
  for (int idx = tid; idx < 16 * DDIM; idx += 256) {
    int m = idx / DDIM;
    int k = idx - m * DDIM;
    xs[idx] = ld<MODE>(x, (size_t)toks[m] * DDIM + k);
  }
  __syncthreads();
  int lane = tid & 63, tg = tid >> 6;
  int j0 = blockIdx.y * 256 + lane * 4;
  size_t wbase = (size_t)e * DDIM * HDIM + j0;
  float acc[4][4];
#pragma unroll
  for (int i = 0; i < 4; ++i)
#pragma unroll
    for (int q = 0; q < 4; ++q) acc[i][q] = 0.f;
  const float* xbase = &xs[tg * 4 * DDIM];
#pragma unroll 4
  for (int k = 0; k < DDIM; ++k) {
    float wr[4];
    ld4<MODE>(W1, wbase + (size_t)k * HDIM, wr);
#pragma unroll
    for (int i = 0; i < 4; ++i) {
      float xv = xbase[i * DDIM + k];
      acc[i][0] += xv * wr[0];
      acc[i][1] += xv * wr[1];
      acc[i][2] += xv * wr[2];
      acc[i][3] += xv * wr[3];
    }
  }
  float br[4];
  ld4<MODE>(b1, (size_t)e * HDIM + j0, br);
#pragma unroll
  for (int i = 0; i < 4; ++i) {
    int m = tg * 4 + i;
    if (m >= mv) continue;
    size_t slot = (size_t)(start + m);
    ushort4 hv;
    hv.x = f2bf(gelu_f(acc[i][0] + br[0]));
    hv.y = f2bf(gelu_f(acc[i][1] + br[1]));
    hv.z = f2bf(gelu_f(acc[i][2] + br[2]));
    hv.w = f2bf(gelu_f(acc[i][3] + br[3]));
    *(ushort4*)&h[slot * HDIM + j0] = hv;
  }
}

// ---------------- grouped FFN layer 2: ffn = topp*(h @ W2[e] + b2[e]); v += ffn.Wv
template <int MODE>
__global__ __launch_bounds__(256) void k_ffn2(
    const ushort_t* __restrict__ h, const void* __restrict__ W2,
    const void* __restrict__ b2, const float* __restrict__ topp,
    const void* __restrict__ Wv, const int* __restrict__ flag,
    const int* __restrict__ meta, const int* __restrict__ tiles,
    const int* __restrict__ perm, float* __restrict__ ffn, float* __restrict__ v) {
  if (flag[0] != MODE) return;
  __shared__ float hs[16 * DDIM];
  __shared__ int toks[16];
  if (blockIdx.x >= meta[0]) return;
  int desc = tiles[blockIdx.x];
  int e = desc >> 20, mv = (desc >> 12) & 31, start = desc & 0xFFF;
  int tid = threadIdx.x;
  if (tid < 16) toks[tid] = perm[start + ((tid < mv) ? tid : 0)];
  __syncthreads();
  int lane = tid & 63, tg = tid >> 6;
  int j0 = blockIdx.y * 256 + lane * 4;  // blockIdx.y in 0..2
  float acc[4][4];
#pragma unroll
  for (int i = 0; i < 4; ++i)
#pragma unroll
    for (int q = 0; q < 4; ++q) acc[i][q] = 0.f;
  const float* hbase = &hs[tg * 4 * DDIM];
  for (int c4 = 0; c4 < 4; ++c4) {
    for (int idx = tid; idx < 16 * DDIM; idx += 256) {
      int m = idx / DDIM;
      int k = idx - m * DDIM;
      size_t slot = (size_t)(start + ((m < mv) ? m : 0));
      hs[idx] = bf2f(h[slot * HDIM + c4 * DDIM + k]);
    }
    __syncthreads();
    size_t wbase = (size_t)e * HDIM * DDIM + (size_t)(c4 * DDIM) * DDIM + j0;
#pragma unroll 4
    for (int k = 0; k < DDIM; ++k) {
      float wr[4];
      ld4<MODE>(W2, wbase + (size_t)k * DDIM, wr);
#pragma unroll
      for (int i = 0; i < 4; ++i) {
        float hv = hbase[i * DDIM + k];
        acc[i][0] += hv * wr[0];
        acc[i][1] += hv * wr[1];
        acc[i][2] += hv * wr[2];
        acc[i][3] += hv * wr[3];
      }
    }
    __syncthreads();
  }
  float wv[4], br[4];
  ld4<MODE>(Wv, j0, wv);
  ld4<MODE>(b2, (size_t)e * DDIM + j0, br);
#pragma unroll
  for (int i = 0; i < 4; ++i) {
    int m = tg * 4 + i;
    bool valid = (m < mv);  // wave-uniform
    int tok = toks[(m < mv) ? m : 0];
    float tp = topp[tok];
    float f0 = tp * (acc[i][0] + br[0]);
    float f1 = tp * (acc[i][1] + br[1]);
    float f2 = tp * (acc[i][2] + br[2]);
    float f3 = tp * (acc[i][3] + br[3]);
    if (valid) {
      float4 fv = make_float4(f0, f1, f2, f3);
      *(float4*)&ffn[(size_t)tok * DDIM + j0] = fv;
    }
    float pv = f0 * wv[0] + f1 * wv[1] + f2 * wv[2] + f3 * wv[3];
#pragma unroll
    for (int off = 32; off > 0; off >>= 1) pv += __shfl_down(pv, off, 64);
    if (valid && lane == 0) atomicAdd(&v[tok], pv);
  }
}

// ---------------- BK continued-fraction scans (sequential) ----------------------
__global__ void k_bk(const float* __restrict__ v, float* __restrict__ Ar,
                     float* __restrict__ Ai, float* __restrict__ Br,
                     float* __restrict__ Bi) {
  int tid = threadIdx.x;
  if (tid >= 4) return;
  int b = tid >> 1, rev = tid & 1;
  const float* vb = v + b * SEQ;
  float ar = 1e18f, ai = 0.f;
  for (int s = 0; s < SEQ; ++s) {
    int n = rev ? (SEQ - 1 - s) : s;
    float vc = fminf(3.f, fmaxf(-3.f, vb[n]));
    float den = ar * ar + ai * ai;
    ar = vc - ar / den;
    ai = -1.f + ai / den;
    if (rev) {
      Br[b * SEQ + n] = ar;
      Bi[b * SEQ + n] = ai;
    } else {
      Ar[b * SEQ + n] = ar;
      Ai[b * SEQ + n] = ai;
    }
  }
}

// ---------------- final: out = ffn + bk_scale*(feats @ Wo + bo) -----------------
template <int MODE>
__global__ __launch_bounds__(256) void k_final(
    const float* __restrict__ ffn, const float* __restrict__ v,
    const float* __restrict__ Ar, const float* __restrict__ Ai,
    const float* __restrict__ Br, const float* __restrict__ Bi,
    const float* __restrict__ score, const float* __restrict__ thr,
    const void* __restrict__ Wo, const void* __restrict__ bo,
    const void* __restrict__ bk, const int* __restrict__ flag,
    void* __restrict__ out) {
  if (flag[0] != MODE) return;
  int t = blockIdx.x;
  int b = t >> 11;
  float vc = fminf(3.f, fmaxf(-3.f, v[t]));
  float cr = Ar[t] + Br[t] - vc;
  float ci = Ai[t] + Bi[t] + 1.f;  // - (-eta)
  float den = cr * cr + ci * ci;
  float gr = cr / den, gi = -ci / den;
  bool m = (score[t] >= thr[b]);
  float fr = m ? fminf(10.f, fmaxf(-10.f, gr)) : 0.f;
  float fi = m ? fminf(10.f, fmaxf(-10.f, gi)) : 0.f;
  float bs = ld<MODE>(bk, 0);
  for (int d = threadIdx.x; d < DDIM; d += 256) {
    float o = ffn[(size_t)t * DDIM + d] +
              bs * (fr * ld<MODE>(Wo, d) + fi * ld<MODE>(Wo, DDIM + d) +
                    ld<MODE>(bo, d));
    st<MODE>(out, (size_t)t * DDIM + d, o);
  }
}

extern "C" void kernel_launch(void* const* d_in, const int* in_sizes, int n_in,
                              void* d_out, int out_size, void* d_ws, size_t ws_size,
                              hipStream_t stream) {
  const void* x  = d_in[0];
  const void* Wg = d_in[1];
  const void* bg = d_in[2];
  const void* W1 = d_in[3];
  const void* b1 = d_in[4];
  const void* W2 = d_in[5];
  const void* b2 = d_in[6];
  const void* Wv = d_in[7];
  const void* bv = d_in[8];
  const void* Wm = d_in[9];
  const void* bm = d_in[10];
  const void* Wo = d_in[11];
  const void* bo = d_in[12];
  const void* bk = d_in[13];

  unsigned char* w = (unsigned char*)d_ws;
  int*   expert = (int*)(w + 0);           // 16 KB
  float* topp   = (float*)(w + 16384);
  float* score  = (float*)(w + 32768);
  float* v      = (float*)(w + 49152);
  float* Ar     = (float*)(w + 65536);
  float* Ai     = (float*)(w + 81920);
  float* Br     = (float*)(w + 98304);
  float* Bi     = (float*)(w + 114688);
  float* thr    = (float*)(w + 131072);    // 2 floats
  int*   meta   = (int*)(w + 131136);
  int*   flag   = (int*)(w + 131160);
  int*   tiles  = (int*)(w + 131200);      // 264 ints
  int*   perm   = (int*)(w + 132352);      // 16 KB
  ushort_t* h   = (ushort_t*)(w + 148992); // 4096*3072 bf16 = 24 MB
  float* ffn    = (float*)(w + 25315072);  // 4096*768 f32 = 12 MB (ends ~37.9 MB)

  k_detect<<<1, 64, 0, stream>>>((const uint32*)x, flag);

  k_gate<0><<<1024, 256, 0, stream>>>(x, Wg, bg, Wm, bm, bv, flag, expert, topp, score, v);
  k_gate<1><<<1024, 256, 0, stream>>>(x, Wg, bg, Wm, bm, bv, flag, expert, topp, score, v);

  k_thr<<<2, 256, 0, stream>>>(score, thr);
  k_bucket<<<1, 256, 0, stream>>>(expert, meta, tiles, perm);

  k_ffn1<0><<<dim3(NT_MAX, 12), 256, 0, stream>>>(x, W1, b1, flag, meta, tiles, perm, h);
  k_ffn1<1><<<dim3(NT_MAX, 12), 256, 0, stream>>>(x, W1, b1, flag, meta, tiles, perm, h);

  k_ffn2<0><<<dim3(NT_MAX, 3), 256, 0, stream>>>(h, W2, b2, topp, Wv, flag, meta, tiles, perm, ffn, v);
  k_ffn2<1><<<dim3(NT_MAX, 3), 256, 0, stream>>>(h, W2, b2, topp, Wv, flag, meta, tiles, perm, ffn, v);

  k_bk<<<1, 64, 0, stream>>>(v, Ar, Ai, Br, Bi);

  k_final<0><<<NTOK, 256, 0, stream>>>(ffn, v, Ar, Ai, Br, Bi, score, thr, Wo, bo, bk, flag, d_out);
  k_final<1><<<NTOK, 256, 0, stream>>>(ffn, v, Ar, Ai, Br, Bi, score, thr, Wo, bo, bk, flag, d_out);
}

// Round 3
// 667.918 us; speedup vs baseline: 2.7435x; 2.7435x over previous
//
#include <hip/hip_runtime.h>

typedef unsigned short ushort_t;
typedef unsigned int uint32;

#define NTOK 4096
#define SEQ 2048
#define DDIM 768
#define HDIM 3072
#define NEXP 8
#define KKEEP 819
#define MTILE 128
#define MAXTILES 40
#define MAXSLOTS 5120

typedef __attribute__((ext_vector_type(8))) short bfrag8;   // 8 bf16 (4 VGPRs)
typedef __attribute__((ext_vector_type(4))) float facc4;    // 4 fp32 acc

__device__ __forceinline__ ushort_t f2bf(float f) {
  uint32 x = __float_as_uint(f);
  uint32 r = (x + 0x7FFFu + ((x >> 16) & 1u)) >> 16;
  return (ushort_t)r;
}
__device__ __forceinline__ float gelu_f(float u) {
  float u3 = u * u * u;
  return 0.5f * u * (1.f + tanhf(0.7978845608028654f * (u + 0.044715f * u3)));
}

// async global->LDS, 16 bytes per lane, LDS dest contiguous in lane order
#define GL2LDS(gp, lp)                                                        \
  __builtin_amdgcn_global_load_lds(                                           \
      (const __attribute__((address_space(1))) void*)(gp),                    \
      (__attribute__((address_space(3))) void*)(lp), 16, 0, 0)

// ---------------- gate: softmax top-1 expert + mask score -----------------------
__global__ __launch_bounds__(256) void k_gate(
    const float* __restrict__ x, const float* __restrict__ Wg,
    const float* __restrict__ bg, const float* __restrict__ Wm,
    const float* __restrict__ bm, int* __restrict__ expert,
    float* __restrict__ topp, float* __restrict__ score) {
  int tid = threadIdx.x, lane = tid & 63, w = tid >> 6;
  int t = blockIdx.x * 4 + w;
  float g[8];
#pragma unroll
  for (int e = 0; e < 8; ++e) g[e] = 0.f;
  float sm = 0.f;
  for (int d = lane; d < DDIM; d += 64) {
    float xv = x[(size_t)t * DDIM + d];
    float4 w0 = *(const float4*)(Wg + d * 8);
    float4 w1 = *(const float4*)(Wg + d * 8 + 4);
    g[0] += xv * w0.x; g[1] += xv * w0.y; g[2] += xv * w0.z; g[3] += xv * w0.w;
    g[4] += xv * w1.x; g[5] += xv * w1.y; g[6] += xv * w1.z; g[7] += xv * w1.w;
    sm += xv * Wm[d];
  }
#pragma unroll
  for (int e = 0; e < 8; ++e) {
#pragma unroll
    for (int off = 32; off > 0; off >>= 1) g[e] += __shfl_down(g[e], off, 64);
  }
#pragma unroll
  for (int off = 32; off > 0; off >>= 1) sm += __shfl_down(sm, off, 64);
  if (lane == 0) {
    float l[8];
#pragma unroll
    for (int e = 0; e < 8; ++e) l[e] = g[e] + bg[e];
    int am = 0;
    float mx = l[0];
#pragma unroll
    for (int e = 1; e < 8; ++e) {
      if (l[e] > mx) { mx = l[e]; am = e; }  // first-max = jnp.argmax
    }
    float s = 0.f;
#pragma unroll
    for (int e = 0; e < 8; ++e) s += expf(l[e] - mx);
    expert[t] = am;
    topp[t] = 1.f / s;
    float z = sm + bm[0];
    score[t] = 1.f / (1.f + expf(-z));
  }
}

// ---------------- top-K threshold via bitonic sort ------------------------------
__global__ __launch_bounds__(256) void k_thr(const float* __restrict__ score,
                                             float* __restrict__ thr) {
  __shared__ float s[SEQ];
  int b = blockIdx.x, tid = threadIdx.x;
  for (int i = tid; i < SEQ; i += 256) s[i] = score[b * SEQ + i];
  __syncthreads();
  for (int k = 2; k <= SEQ; k <<= 1) {
    for (int j = k >> 1; j > 0; j >>= 1) {
      for (int i = tid; i < SEQ; i += 256) {
        int ixj = i ^ j;
        if (ixj > i) {
          float a = s[i], c = s[ixj];
          bool up = ((i & k) == 0);
          if ((a > c) == up) { s[i] = c; s[ixj] = a; }
        }
      }
      __syncthreads();
    }
  }
  if (tid == 0) thr[b] = s[SEQ - KKEEP];
}

// ---------------- bucket tokens, 128-padded slots, tile descriptors -------------
__global__ __launch_bounds__(256) void k_bucket(const int* __restrict__ expert,
                                                int* __restrict__ meta,
                                                int* __restrict__ tiles,
                                                int* __restrict__ slot_token) {
  __shared__ int cnt[NEXP];
  __shared__ int off[NEXP];
  int tid = threadIdx.x;
  if (tid < NEXP) cnt[tid] = 0;
  __syncthreads();
  for (int t = tid; t < NTOK; t += 256) atomicAdd(&cnt[expert[t]], 1);
  __syncthreads();
  if (tid == 0) {
    int run = 0, nt = 0;
    for (int e = 0; e < NEXP; ++e) {
      off[e] = run;
      int c = cnt[e];
      int padded = (c + MTILE - 1) / MTILE * MTILE;
      for (int s = 0; s < padded; s += MTILE) tiles[nt++] = (e << 16) | (run + s);
      run += padded;
    }
    meta[0] = nt;
    meta[1] = run;
  }
  __syncthreads();
  for (int s = tid; s < MAXSLOTS; s += 256) slot_token[s] = -1;
  __syncthreads();
  for (int t = tid; t < NTOK; t += 256) {
    int p = atomicAdd(&off[expert[t]], 1);
    slot_token[p] = t;
  }
}

// ---------------- gather x -> expert-sorted bf16 rows (zero pad rows) -----------
__global__ __launch_bounds__(256) void k_xperm(const float* __restrict__ x,
                                               const int* __restrict__ slot_token,
                                               ushort_t* __restrict__ xp) {
  int slot = blockIdx.x;
  int tok = slot_token[slot];
  for (int d = threadIdx.x; d < DDIM; d += 256) {
    float v = (tok >= 0) ? x[(size_t)tok * DDIM + d] : 0.f;
    xp[(size_t)slot * DDIM + d] = f2bf(v);
  }
}

// ---------------- weight convert + transpose: fp32 [e][K][N] -> bf16 [e][N][K] --
__global__ __launch_bounds__(256) void k_wt(const float* __restrict__ src,
                                            ushort_t* __restrict__ dst, int K,
                                            int N) {
  __shared__ float t[64][65];
  int e = blockIdx.z;
  int k0 = blockIdx.x * 64, n0 = blockIdx.y * 64;
  const float* S = src + (size_t)e * K * N;
  ushort_t* D = dst + (size_t)e * N * K;
  int tid = threadIdx.x;
  int r = tid >> 4, c4 = (tid & 15) * 4;
#pragma unroll
  for (int it = 0; it < 4; ++it) {
    int k = r + it * 16;
    float4 v = *(const float4*)(S + (size_t)(k0 + k) * N + n0 + c4);
    t[k][c4] = v.x; t[k][c4 + 1] = v.y; t[k][c4 + 2] = v.z; t[k][c4 + 3] = v.w;
  }
  __syncthreads();
#pragma unroll
  for (int it = 0; it < 4; ++it) {
    int n = r + it * 16;
    ushort4 o;
    o.x = f2bf(t[c4][n]); o.y = f2bf(t[c4 + 1][n]);
    o.z = f2bf(t[c4 + 2][n]); o.w = f2bf(t[c4 + 3][n]);
    *(ushort4*)(D + (size_t)(n0 + n) * K + k0 + c4) = o;
  }
}

// ---------------- grouped MFMA GEMM layer 1: h = gelu(xp @ W1 + b1) -------------
// A = xp [slot][768] bf16, B = W1t [e][n<3072][k<768] bf16, 128x128 tile, BK=32
__global__ __launch_bounds__(256) void k_gemm1(
    const ushort_t* __restrict__ xp, const ushort_t* __restrict__ Wt,
    const float* __restrict__ b1, const int* __restrict__ meta,
    const int* __restrict__ tiles, ushort_t* __restrict__ h) {
  __shared__ ushort_t As[128 * 32];
  __shared__ ushort_t Bs[128 * 32];
  if ((int)blockIdx.x >= meta[0]) return;
  int desc = tiles[blockIdx.x];
  int e = desc >> 16, slot0 = desc & 0xFFFF;
  int n0 = blockIdx.y * 128;
  int tid = threadIdx.x;
  int lane = tid & 63, w = tid >> 6;
  int mq = (w & 1) << 6, nq = (w >> 1) << 6;
  int mrow = lane & 15, quad = lane >> 4;
  int r0 = tid >> 2, s0 = (tid & 3) << 3;
  const ushort_t* Ag = xp + (size_t)slot0 * 768;
  const ushort_t* Bg = Wt + ((size_t)e * 3072 + n0) * 768;
  facc4 acc[4][4];
  facc4 zero = {0.f, 0.f, 0.f, 0.f};
#pragma unroll
  for (int i = 0; i < 4; ++i)
#pragma unroll
    for (int j = 0; j < 4; ++j) acc[i][j] = zero;
  for (int k0 = 0; k0 < 768; k0 += 32) {
    GL2LDS(Ag + (size_t)r0 * 768 + k0 + s0, As + tid * 8);
    GL2LDS(Ag + (size_t)(r0 + 64) * 768 + k0 + s0, As + (tid + 256) * 8);
    GL2LDS(Bg + (size_t)r0 * 768 + k0 + s0, Bs + tid * 8);
    GL2LDS(Bg + (size_t)(r0 + 64) * 768 + k0 + s0, Bs + (tid + 256) * 8);
    __syncthreads();
    bfrag8 a[4], b[4];
#pragma unroll
    for (int i = 0; i < 4; ++i)
      a[i] = *(const bfrag8*)(As + ((mq + i * 16 + mrow) << 5) + (quad << 3));
#pragma unroll
    for (int j = 0; j < 4; ++j)
      b[j] = *(const bfrag8*)(Bs + ((nq + j * 16 + mrow) << 5) + (quad << 3));
#pragma unroll
    for (int i = 0; i < 4; ++i)
#pragma unroll
      for (int j = 0; j < 4; ++j)
        acc[i][j] = __builtin_amdgcn_mfma_f32_16x16x32_bf16(a[i], b[j],
                                                            acc[i][j], 0, 0, 0);
    __syncthreads();
  }
  const float* bb = b1 + (size_t)e * 3072 + n0;
#pragma unroll
  for (int i = 0; i < 4; ++i) {
    int mo = mq + i * 16 + (quad << 2);
#pragma unroll
    for (int j = 0; j < 4; ++j) {
      int nc = nq + j * 16 + mrow;
      float bias = bb[nc];
#pragma unroll
      for (int r = 0; r < 4; ++r) {
        float val = gelu_f(acc[i][j][r] + bias);
        h[(size_t)(slot0 + mo + r) * 3072 + n0 + nc] = f2bf(val);
      }
    }
  }
}

// ---------------- grouped MFMA GEMM layer 2: out = topp*(h @ W2 + b2) -----------
// A = h [slot][3072] bf16, B = W2t [e][n<768][k<3072] bf16
__global__ __launch_bounds__(256) void k_gemm2(
    const ushort_t* __restrict__ h, const ushort_t* __restrict__ Wt,
    const float* __restrict__ b2, const float* __restrict__ topp,
    const int* __restrict__ meta, const int* __restrict__ tiles,
    const int* __restrict__ slot_token, float* __restrict__ outf) {
  __shared__ ushort_t As[128 * 32];
  __shared__ ushort_t Bs[128 * 32];
  if ((int)blockIdx.x >= meta[0]) return;
  int desc = tiles[blockIdx.x];
  int e = desc >> 16, slot0 = desc & 0xFFFF;
  int n0 = blockIdx.y * 128;
  int tid = threadIdx.x;
  int lane = tid & 63, w = tid >> 6;
  int mq = (w & 1) << 6, nq = (w >> 1) << 6;
  int mrow = lane & 15, quad = lane >> 4;
  int r0 = tid >> 2, s0 = (tid & 3) << 3;
  const ushort_t* Ag = h + (size_t)slot0 * 3072;
  const ushort_t* Bg = Wt + ((size_t)e * 768 + n0) * 3072;
  facc4 acc[4][4];
  facc4 zero = {0.f, 0.f, 0.f, 0.f};
#pragma unroll
  for (int i = 0; i < 4; ++i)
#pragma unroll
    for (int j = 0; j < 4; ++j) acc[i][j] = zero;
  for (int k0 = 0; k0 < 3072; k0 += 32) {
    GL2LDS(Ag + (size_t)r0 * 3072 + k0 + s0, As + tid * 8);
    GL2LDS(Ag + (size_t)(r0 + 64) * 3072 + k0 + s0, As + (tid + 256) * 8);
    GL2LDS(Bg + (size_t)r0 * 3072 + k0 + s0, Bs + tid * 8);
    GL2LDS(Bg + (size_t)(r0 + 64) * 3072 + k0 + s0, Bs + (tid + 256) * 8);
    __syncthreads();
    bfrag8 a[4], b[4];
#pragma unroll
    for (int i = 0; i < 4; ++i)
      a[i] = *(const bfrag8*)(As + ((mq + i * 16 + mrow) << 5) + (quad << 3));
#pragma unroll
    for (int j = 0; j < 4; ++j)
      b[j] = *(const bfrag8*)(Bs + ((nq + j * 16 + mrow) << 5) + (quad << 3));
#pragma unroll
    for (int i = 0; i < 4; ++i)
#pragma unroll
      for (int j = 0; j < 4; ++j)
        acc[i][j] = __builtin_amdgcn_mfma_f32_16x16x32_bf16(a[i], b[j],
                                                            acc[i][j], 0, 0, 0);
    __syncthreads();
  }
  const float* bb = b2 + (size_t)e * 768 + n0;
#pragma unroll
  for (int i = 0; i < 4; ++i) {
    int mo = mq + i * 16 + (quad << 2);
#pragma unroll
    for (int r = 0; r < 4; ++r) {
      int slot = slot0 + mo + r;
      int tok = slot_token[slot];
      if (tok < 0) continue;
      float tp = topp[tok];
#pragma unroll
      for (int j = 0; j < 4; ++j) {
        int nc = nq + j * 16 + mrow;
        outf[(size_t)tok * 768 + n0 + nc] = tp * (acc[i][j][r] + bb[nc]);
      }
    }
  }
}

// ---------------- v = bv + ffn . Wv ---------------------------------------------
__global__ __launch_bounds__(256) void k_vdot(const float* __restrict__ ffn,
                                              const float* __restrict__ Wv,
                                              const float* __restrict__ bv,
                                              float* __restrict__ v) {
  int t = blockIdx.x * 4 + (threadIdx.x >> 6);
  int lane = threadIdx.x & 63;
  float s = 0.f;
  for (int d = lane; d < DDIM; d += 64) s += ffn[(size_t)t * DDIM + d] * Wv[d];
#pragma unroll
  for (int off = 32; off > 0; off >>= 1) s += __shfl_down(s, off, 64);
  if (lane == 0) v[t] = s + bv[0];
}

// ---------------- BK continued-fraction scans (sequential) ----------------------
__global__ void k_bk(const float* __restrict__ v, float* __restrict__ Ar,
                     float* __restrict__ Ai, float* __restrict__ Br,
                     float* __restrict__ Bi) {
  int tid = threadIdx.x;
  if (tid >= 4) return;
  int b = tid >> 1, rev = tid & 1;
  const float* vb = v + b * SEQ;
  float ar = 1e18f, ai = 0.f;
  for (int s = 0; s < SEQ; ++s) {
    int n = rev ? (SEQ - 1 - s) : s;
    float vc = fminf(3.f, fmaxf(-3.f, vb[n]));
    float den = ar * ar + ai * ai;
    ar = vc - ar / den;
    ai = -1.f + ai / den;
    if (rev) {
      Br[b * SEQ + n] = ar;
      Bi[b * SEQ + n] = ai;
    } else {
      Ar[b * SEQ + n] = ar;
      Ai[b * SEQ + n] = ai;
    }
  }
}

// ---------------- final (in place on d_out): out += bk_scale*(feats@Wo+bo) ------
__global__ __launch_bounds__(256) void k_final(
    float* __restrict__ outf, const float* __restrict__ v,
    const float* __restrict__ Ar, const float* __restrict__ Ai,
    const float* __restrict__ Br, const float* __restrict__ Bi,
    const float* __restrict__ score, const float* __restrict__ thr,
    const float* __restrict__ Wo, const float* __restrict__ bo,
    const float* __restrict__ bk) {
  int t = blockIdx.x;
  int b = t >> 11;
  float vc = fminf(3.f, fmaxf(-3.f, v[t]));
  float cr = Ar[t] + Br[t] - vc;
  float ci = Ai[t] + Bi[t] + 1.f;
  float den = cr * cr + ci * ci;
  float gr = cr / den, gi = -ci / den;
  bool m = (score[t] >= thr[b]);
  float fr = m ? fminf(10.f, fmaxf(-10.f, gr)) : 0.f;
  float fi = m ? fminf(10.f, fmaxf(-10.f, gi)) : 0.f;
  float bs = bk[0];
  for (int d = threadIdx.x; d < DDIM; d += 256) {
    float o = outf[(size_t)t * DDIM + d] +
              bs * (fr * Wo[d] + fi * Wo[DDIM + d] + bo[d]);
    outf[(size_t)t * DDIM + d] = o;
  }
}

extern "C" void kernel_launch(void* const* d_in, const int* in_sizes, int n_in,
                              void* d_out, int out_size, void* d_ws, size_t ws_size,
                              hipStream_t stream) {
  const float* x  = (const float*)d_in[0];
  const float* Wg = (const float*)d_in[1];
  const float* bg = (const float*)d_in[2];
  const float* W1 = (const float*)d_in[3];
  const float* b1 = (const float*)d_in[4];
  const float* W2 = (const float*)d_in[5];
  const float* b2 = (const float*)d_in[6];
  const float* Wv = (const float*)d_in[7];
  const float* bv = (const float*)d_in[8];
  const float* Wm = (const float*)d_in[9];
  const float* bm = (const float*)d_in[10];
  const float* Wo = (const float*)d_in[11];
  const float* bo = (const float*)d_in[12];
  const float* bk = (const float*)d_in[13];
  float* outf = (float*)d_out;

  unsigned char* w = (unsigned char*)d_ws;
  int*   expert     = (int*)(w + 0);
  float* topp       = (float*)(w + 16384);
  float* score      = (float*)(w + 32768);
  float* v          = (float*)(w + 49152);
  float* Ar         = (float*)(w + 65536);
  float* Ai         = (float*)(w + 81920);
  float* Br         = (float*)(w + 98304);
  float* Bi         = (float*)(w + 114688);
  float* thr        = (float*)(w + 131072);
  int*   meta       = (int*)(w + 131104);
  int*   tiles      = (int*)(w + 131136);
  int*   slot_token = (int*)(w + 131328);            // 5120 ints
  ushort_t* xp      = (ushort_t*)(w + 152064);       // 5120*768  bf16 = 7.9 MB
  ushort_t* h       = (ushort_t*)(w + 8016384);      // 5120*3072 bf16 = 31.5 MB
  ushort_t* Wt      = (ushort_t*)(w + 39473664);     // 8*3072*768 bf16 = 37.7 MB (reused)
  // total ~77.3 MB

  k_gate<<<1024, 256, 0, stream>>>(x, Wg, bg, Wm, bm, expert, topp, score);
  k_thr<<<2, 256, 0, stream>>>(score, thr);
  k_bucket<<<1, 256, 0, stream>>>(expert, meta, tiles, slot_token);
  k_xperm<<<MAXSLOTS, 256, 0, stream>>>(x, slot_token, xp);

  k_wt<<<dim3(12, 48, 8), 256, 0, stream>>>(W1, Wt, 768, 3072);
  k_gemm1<<<dim3(MAXTILES, 24), 256, 0, stream>>>(xp, Wt, b1, meta, tiles, h);

  k_wt<<<dim3(48, 12, 8), 256, 0, stream>>>(W2, Wt, 3072, 768);
  k_gemm2<<<dim3(MAXTILES, 6), 256, 0, stream>>>(h, Wt, b2, topp, meta, tiles,
                                                 slot_token, outf);

  k_vdot<<<1024, 256, 0, stream>>>(outf, Wv, bv, v);
  k_bk<<<1, 64, 0, stream>>>(v, Ar, Ai, Br, Bi);
  k_final<<<NTOK, 256, 0, stream>>>(outf, v, Ar, Ai, Br, Bi, score, thr, Wo, bo, bk);
}

// Round 4
// 431.235 us; speedup vs baseline: 4.2493x; 1.5488x over previous
//
#include <hip/hip_runtime.h>

typedef unsigned short ushort_t;
typedef unsigned int uint32;

#define NTOK 4096
#define SEQ 2048
#define DDIM 768
#define HDIM 3072
#define NEXP 8
#define KKEEP 819
#define MTILE 128
#define MAXTILES 40
#define MAXSLOTS 5120

typedef __attribute__((ext_vector_type(8))) short bfrag8;   // 8 bf16 (4 VGPRs)
typedef __attribute__((ext_vector_type(4))) float facc4;    // 4 fp32 acc

__device__ __forceinline__ ushort_t f2bf(float f) {
  uint32 x = __float_as_uint(f);
  uint32 r = (x + 0x7FFFu + ((x >> 16) & 1u)) >> 16;
  return (ushort_t)r;
}
__device__ __forceinline__ float gelu_f(float u) {
  float u3 = u * u * u;
  return 0.5f * u * (1.f + tanhf(0.7978845608028654f * (u + 0.044715f * u3)));
}

// async global->LDS, 16 bytes per lane, LDS dest contiguous in lane order
#define GL2LDS(gp, lp)                                                        \
  __builtin_amdgcn_global_load_lds(                                           \
      (const __attribute__((address_space(1))) void*)(gp),                    \
      (__attribute__((address_space(3))) void*)(lp), 16, 0, 0)

// ---------------- gate: softmax top-1 expert + mask score -----------------------
__global__ __launch_bounds__(256) void k_gate(
    const float* __restrict__ x, const float* __restrict__ Wg,
    const float* __restrict__ bg, const float* __restrict__ Wm,
    const float* __restrict__ bm, int* __restrict__ expert,
    float* __restrict__ topp, float* __restrict__ score) {
  int tid = threadIdx.x, lane = tid & 63, w = tid >> 6;
  int t = blockIdx.x * 4 + w;
  float g[8];
#pragma unroll
  for (int e = 0; e < 8; ++e) g[e] = 0.f;
  float sm = 0.f;
  for (int d = lane; d < DDIM; d += 64) {
    float xv = x[(size_t)t * DDIM + d];
    float4 w0 = *(const float4*)(Wg + d * 8);
    float4 w1 = *(const float4*)(Wg + d * 8 + 4);
    g[0] += xv * w0.x; g[1] += xv * w0.y; g[2] += xv * w0.z; g[3] += xv * w0.w;
    g[4] += xv * w1.x; g[5] += xv * w1.y; g[6] += xv * w1.z; g[7] += xv * w1.w;
    sm += xv * Wm[d];
  }
#pragma unroll
  for (int e = 0; e < 8; ++e) {
#pragma unroll
    for (int off = 32; off > 0; off >>= 1) g[e] += __shfl_down(g[e], off, 64);
  }
#pragma unroll
  for (int off = 32; off > 0; off >>= 1) sm += __shfl_down(sm, off, 64);
  if (lane == 0) {
    float l[8];
#pragma unroll
    for (int e = 0; e < 8; ++e) l[e] = g[e] + bg[e];
    int am = 0;
    float mx = l[0];
#pragma unroll
    for (int e = 1; e < 8; ++e) {
      if (l[e] > mx) { mx = l[e]; am = e; }  // first-max = jnp.argmax
    }
    float s = 0.f;
#pragma unroll
    for (int e = 0; e < 8; ++e) s += expf(l[e] - mx);
    expert[t] = am;
    topp[t] = 1.f / s;
    float z = sm + bm[0];
    score[t] = 1.f / (1.f + expf(-z));
  }
}

// ---------------- top-K threshold via bitonic sort ------------------------------
__global__ __launch_bounds__(256) void k_thr(const float* __restrict__ score,
                                             float* __restrict__ thr) {
  __shared__ float s[SEQ];
  int b = blockIdx.x, tid = threadIdx.x;
  for (int i = tid; i < SEQ; i += 256) s[i] = score[b * SEQ + i];
  __syncthreads();
  for (int k = 2; k <= SEQ; k <<= 1) {
    for (int j = k >> 1; j > 0; j >>= 1) {
      for (int i = tid; i < SEQ; i += 256) {
        int ixj = i ^ j;
        if (ixj > i) {
          float a = s[i], c = s[ixj];
          bool up = ((i & k) == 0);
          if ((a > c) == up) { s[i] = c; s[ixj] = a; }
        }
      }
      __syncthreads();
    }
  }
  if (tid == 0) thr[b] = s[SEQ - KKEEP];
}

// ---------------- bucket tokens, 128-padded slots, tile descriptors -------------
__global__ __launch_bounds__(256) void k_bucket(const int* __restrict__ expert,
                                                int* __restrict__ meta,
                                                int* __restrict__ tiles,
                                                int* __restrict__ slot_token) {
  __shared__ int cnt[NEXP];
  __shared__ int off[NEXP];
  int tid = threadIdx.x;
  if (tid < NEXP) cnt[tid] = 0;
  __syncthreads();
  for (int t = tid; t < NTOK; t += 256) atomicAdd(&cnt[expert[t]], 1);
  __syncthreads();
  if (tid == 0) {
    int run = 0, nt = 0;
    for (int e = 0; e < NEXP; ++e) {
      off[e] = run;
      int c = cnt[e];
      int padded = (c + MTILE - 1) / MTILE * MTILE;
      for (int s = 0; s < padded; s += MTILE) tiles[nt++] = (e << 16) | (run + s);
      run += padded;
    }
    meta[0] = nt;
    meta[1] = run;
  }
  __syncthreads();
  for (int s = tid; s < MAXSLOTS; s += 256) slot_token[s] = -1;
  __syncthreads();
  for (int t = tid; t < NTOK; t += 256) {
    int p = atomicAdd(&off[expert[t]], 1);
    slot_token[p] = t;
  }
}

// ---------------- gather x -> expert-sorted bf16 rows (zero pad rows) -----------
__global__ __launch_bounds__(256) void k_xperm(const float* __restrict__ x,
                                               const int* __restrict__ slot_token,
                                               ushort_t* __restrict__ xp) {
  int slot = blockIdx.x;
  int tok = slot_token[slot];
  for (int d = threadIdx.x; d < DDIM; d += 256) {
    float v = (tok >= 0) ? x[(size_t)tok * DDIM + d] : 0.f;
    xp[(size_t)slot * DDIM + d] = f2bf(v);
  }
}

// ---------------- weight convert + transpose: fp32 [e][K][N] -> bf16 [e][N][K] --
__global__ __launch_bounds__(256) void k_wt(const float* __restrict__ src,
                                            ushort_t* __restrict__ dst, int K,
                                            int N) {
  __shared__ float t[64][65];
  int e = blockIdx.z;
  int k0 = blockIdx.x * 64, n0 = blockIdx.y * 64;
  const float* S = src + (size_t)e * K * N;
  ushort_t* D = dst + (size_t)e * N * K;
  int tid = threadIdx.x;
  int r = tid >> 4, c4 = (tid & 15) * 4;
#pragma unroll
  for (int it = 0; it < 4; ++it) {
    int k = r + it * 16;
    float4 v = *(const float4*)(S + (size_t)(k0 + k) * N + n0 + c4);
    t[k][c4] = v.x; t[k][c4 + 1] = v.y; t[k][c4 + 2] = v.z; t[k][c4 + 3] = v.w;
  }
  __syncthreads();
#pragma unroll
  for (int it = 0; it < 4; ++it) {
    int n = r + it * 16;
    ushort4 o;
    o.x = f2bf(t[c4][n]); o.y = f2bf(t[c4 + 1][n]);
    o.z = f2bf(t[c4 + 2][n]); o.w = f2bf(t[c4 + 3][n]);
    *(ushort4*)(D + (size_t)(n0 + n) * K + k0 + c4) = o;
  }
}

// ---------------- grouped MFMA GEMM layer 1: h = gelu(xp @ W1 + b1) -------------
// A = xp [slot][768] bf16, B = W1t [e][n<3072][k<768] bf16, 128x128 tile, BK=32
__global__ __launch_bounds__(256) void k_gemm1(
    const ushort_t* __restrict__ xp, const ushort_t* __restrict__ Wt,
    const float* __restrict__ b1, const int* __restrict__ meta,
    const int* __restrict__ tiles, ushort_t* __restrict__ h) {
  __shared__ ushort_t As[128 * 32];
  __shared__ ushort_t Bs[128 * 32];
  if ((int)blockIdx.x >= meta[0]) return;
  int desc = tiles[blockIdx.x];
  int e = desc >> 16, slot0 = desc & 0xFFFF;
  int n0 = blockIdx.y * 128;
  int tid = threadIdx.x;
  int lane = tid & 63, w = tid >> 6;
  int mq = (w & 1) << 6, nq = (w >> 1) << 6;
  int mrow = lane & 15, quad = lane >> 4;
  int r0 = tid >> 2, s0 = (tid & 3) << 3;
  const ushort_t* Ag = xp + (size_t)slot0 * 768;
  const ushort_t* Bg = Wt + ((size_t)e * 3072 + n0) * 768;
  facc4 acc[4][4];
  facc4 zero = {0.f, 0.f, 0.f, 0.f};
#pragma unroll
  for (int i = 0; i < 4; ++i)
#pragma unroll
    for (int j = 0; j < 4; ++j) acc[i][j] = zero;
  for (int k0 = 0; k0 < 768; k0 += 32) {
    GL2LDS(Ag + (size_t)r0 * 768 + k0 + s0, As + tid * 8);
    GL2LDS(Ag + (size_t)(r0 + 64) * 768 + k0 + s0, As + (tid + 256) * 8);
    GL2LDS(Bg + (size_t)r0 * 768 + k0 + s0, Bs + tid * 8);
    GL2LDS(Bg + (size_t)(r0 + 64) * 768 + k0 + s0, Bs + (tid + 256) * 8);
    __syncthreads();
    bfrag8 a[4], b[4];
#pragma unroll
    for (int i = 0; i < 4; ++i)
      a[i] = *(const bfrag8*)(As + ((mq + i * 16 + mrow) << 5) + (quad << 3));
#pragma unroll
    for (int j = 0; j < 4; ++j)
      b[j] = *(const bfrag8*)(Bs + ((nq + j * 16 + mrow) << 5) + (quad << 3));
#pragma unroll
    for (int i = 0; i < 4; ++i)
#pragma unroll
      for (int j = 0; j < 4; ++j)
        acc[i][j] = __builtin_amdgcn_mfma_f32_16x16x32_bf16(a[i], b[j],
                                                            acc[i][j], 0, 0, 0);
    __syncthreads();
  }
  const float* bb = b1 + (size_t)e * 3072 + n0;
#pragma unroll
  for (int i = 0; i < 4; ++i) {
    int mo = mq + i * 16 + (quad << 2);
#pragma unroll
    for (int j = 0; j < 4; ++j) {
      int nc = nq + j * 16 + mrow;
      float bias = bb[nc];
#pragma unroll
      for (int r = 0; r < 4; ++r) {
        float val = gelu_f(acc[i][j][r] + bias);
        h[(size_t)(slot0 + mo + r) * 3072 + n0 + nc] = f2bf(val);
      }
    }
  }
}

// ---------------- grouped MFMA GEMM layer 2: out = topp*(h @ W2 + b2) -----------
// A = h [slot][3072] bf16, B = W2t [e][n<768][k<3072] bf16, 128x64 tile, BK=32
__global__ __launch_bounds__(256) void k_gemm2(
    const ushort_t* __restrict__ h, const ushort_t* __restrict__ Wt,
    const float* __restrict__ b2, const float* __restrict__ topp,
    const int* __restrict__ meta, const int* __restrict__ tiles,
    const int* __restrict__ slot_token, float* __restrict__ outf) {
  __shared__ ushort_t As[128 * 32];
  __shared__ ushort_t Bs[64 * 32];
  if ((int)blockIdx.x >= meta[0]) return;
  int desc = tiles[blockIdx.x];
  int e = desc >> 16, slot0 = desc & 0xFFFF;
  int n0 = blockIdx.y * 64;  // 12 n-blocks
  int tid = threadIdx.x;
  int lane = tid & 63, w = tid >> 6;
  int mq = (w & 1) << 6;   // 0 / 64
  int nq = (w >> 1) << 5;  // 0 / 32
  int mrow = lane & 15, quad = lane >> 4;
  int r0 = tid >> 2, s0 = (tid & 3) << 3;
  const ushort_t* Ag = h + (size_t)slot0 * 3072;
  const ushort_t* Bg = Wt + ((size_t)e * 768 + n0) * 3072;
  facc4 acc[4][2];
  facc4 zero = {0.f, 0.f, 0.f, 0.f};
#pragma unroll
  for (int i = 0; i < 4; ++i)
#pragma unroll
    for (int j = 0; j < 2; ++j) acc[i][j] = zero;
  for (int k0 = 0; k0 < 3072; k0 += 32) {
    GL2LDS(Ag + (size_t)r0 * 3072 + k0 + s0, As + tid * 8);
    GL2LDS(Ag + (size_t)(r0 + 64) * 3072 + k0 + s0, As + (tid + 256) * 8);
    GL2LDS(Bg + (size_t)r0 * 3072 + k0 + s0, Bs + tid * 8);
    __syncthreads();
    bfrag8 a[4], b[2];
#pragma unroll
    for (int i = 0; i < 4; ++i)
      a[i] = *(const bfrag8*)(As + ((mq + i * 16 + mrow) << 5) + (quad << 3));
#pragma unroll
    for (int j = 0; j < 2; ++j)
      b[j] = *(const bfrag8*)(Bs + ((nq + j * 16 + mrow) << 5) + (quad << 3));
#pragma unroll
    for (int i = 0; i < 4; ++i)
#pragma unroll
      for (int j = 0; j < 2; ++j)
        acc[i][j] = __builtin_amdgcn_mfma_f32_16x16x32_bf16(a[i], b[j],
                                                            acc[i][j], 0, 0, 0);
    __syncthreads();
  }
  const float* bb = b2 + (size_t)e * 768 + n0;
#pragma unroll
  for (int i = 0; i < 4; ++i) {
    int mo = mq + i * 16 + (quad << 2);
#pragma unroll
    for (int r = 0; r < 4; ++r) {
      int slot = slot0 + mo + r;
      int tok = slot_token[slot];
      if (tok < 0) continue;
      float tp = topp[tok];
#pragma unroll
      for (int j = 0; j < 2; ++j) {
        int nc = nq + j * 16 + mrow;
        outf[(size_t)tok * 768 + n0 + nc] = tp * (acc[i][j][r] + bb[nc]);
      }
    }
  }
}

// ---------------- v = bv + ffn . Wv ---------------------------------------------
__global__ __launch_bounds__(256) void k_vdot(const float* __restrict__ ffn,
                                              const float* __restrict__ Wv,
                                              const float* __restrict__ bv,
                                              float* __restrict__ v) {
  int t = blockIdx.x * 4 + (threadIdx.x >> 6);
  int lane = threadIdx.x & 63;
  float s = 0.f;
  for (int d = lane; d < DDIM; d += 64) s += ffn[(size_t)t * DDIM + d] * Wv[d];
#pragma unroll
  for (int off = 32; off > 0; off >>= 1) s += __shfl_down(s, off, 64);
  if (lane == 0) v[t] = s + bv[0];
}

// ---------------- BK parallel scan: Mobius matrices, 3-level scan ---------------
// a_i = d_i - 1/a_{i-1}  <=>  M_i = [[d_i,-1],[1,0]] acting projectively.
struct CM {
  float ar, ai, br, bi, cr, ci, dr, di;  // [[a,b],[c,d]] complex
};
__device__ __forceinline__ CM cmmul(const CM& A, const CM& B) {  // A*B
  CM C;
  C.ar = A.ar * B.ar - A.ai * B.ai + A.br * B.cr - A.bi * B.ci;
  C.ai = A.ar * B.ai + A.ai * B.ar + A.br * B.ci + A.bi * B.cr;
  C.br = A.ar * B.br - A.ai * B.bi + A.br * B.dr - A.bi * B.di;
  C.bi = A.ar * B.bi + A.ai * B.br + A.br * B.di + A.bi * B.dr;
  C.cr = A.cr * B.ar - A.ci * B.ai + A.dr * B.cr - A.di * B.ci;
  C.ci = A.cr * B.ai + A.ci * B.ar + A.dr * B.ci + A.di * B.cr;
  C.dr = A.cr * B.br - A.ci * B.bi + A.dr * B.dr - A.di * B.di;
  C.di = A.cr * B.bi + A.ci * B.br + A.dr * B.di + A.di * B.dr;
  return C;
}
__device__ __forceinline__ void cmnorm(CM& A) {
  float m = fmaxf(fmaxf(fmaxf(fabsf(A.ar), fabsf(A.ai)),
                        fmaxf(fabsf(A.br), fabsf(A.bi))),
                  fmaxf(fmaxf(fabsf(A.cr), fabsf(A.ci)),
                        fmaxf(fabsf(A.dr), fabsf(A.di))));
  float s = 1.0f / fmaxf(m, 1e-30f);
  A.ar *= s; A.ai *= s; A.br *= s; A.bi *= s;
  A.cr *= s; A.ci *= s; A.dr *= s; A.di *= s;
}
__device__ __forceinline__ CM cmshfl_up(const CM& A, int off) {
  CM B;
  B.ar = __shfl_up(A.ar, off, 64); B.ai = __shfl_up(A.ai, off, 64);
  B.br = __shfl_up(A.br, off, 64); B.bi = __shfl_up(A.bi, off, 64);
  B.cr = __shfl_up(A.cr, off, 64); B.ci = __shfl_up(A.ci, off, 64);
  B.dr = __shfl_up(A.dr, off, 64); B.di = __shfl_up(A.di, off, 64);
  return B;
}

__global__ __launch_bounds__(256) void k_bkscan(
    const float* __restrict__ v, float* __restrict__ Ar, float* __restrict__ Ai,
    float* __restrict__ Br, float* __restrict__ Bi) {
  int b = blockIdx.x >> 1, rev = blockIdx.x & 1;
  int tid = threadIdx.x, lane = tid & 63, wv = tid >> 6;
  const float* vb = v + b * SEQ;
  float dv[8];
  int sbase = tid * 8;
#pragma unroll
  for (int q = 0; q < 8; ++q) {
    int s = sbase + q;
    int n = rev ? (SEQ - 1 - s) : s;
    dv[q] = fminf(3.f, fmaxf(-3.f, vb[n]));
  }
  // local compose L = M7*...*M0 (step: row0' = d*row0 - row1; row1' = row0)
  CM L;
  L.ar = dv[0]; L.ai = -1.f; L.br = -1.f; L.bi = 0.f;
  L.cr = 1.f; L.ci = 0.f; L.dr = 0.f; L.di = 0.f;
#pragma unroll
  for (int q = 1; q < 8; ++q) {
    float dr = dv[q];
    float nar = dr * L.ar + L.ai - L.cr;   // (dr + i*(-1))*(ar+i*ai) - c
    float nai = dr * L.ai - L.ar - L.ci;
    float nbr = dr * L.br + L.bi - L.dr;
    float nbi = dr * L.bi - L.br - L.di;
    L.cr = L.ar; L.ci = L.ai; L.dr = L.br; L.di = L.bi;
    L.ar = nar; L.ai = nai; L.br = nbr; L.bi = nbi;
  }
  cmnorm(L);
  // wave inclusive scan (compose earlier prefixes on the right)
  CM I = L;
#pragma unroll
  for (int off = 1; off < 64; off <<= 1) {
    CM P = cmshfl_up(I, off);
    if (lane >= off) {
      I = cmmul(I, P);
      cmnorm(I);
    }
  }
  // wave aggregates -> LDS
  __shared__ float wag[4][8];
  if (lane == 63) {
    wag[wv][0] = I.ar; wag[wv][1] = I.ai; wag[wv][2] = I.br; wag[wv][3] = I.bi;
    wag[wv][4] = I.cr; wag[wv][5] = I.ci; wag[wv][6] = I.dr; wag[wv][7] = I.di;
  }
  __syncthreads();
  // exclusive prefix for this thread: E = I_{lane-1} * A_{wv-1} * ... * A_0
  CM E = cmshfl_up(I, 1);
  if (lane == 0) {
    E.ar = 1.f; E.ai = 0.f; E.br = 0.f; E.bi = 0.f;
    E.cr = 0.f; E.ci = 0.f; E.dr = 1.f; E.di = 0.f;
  }
  for (int j = wv - 1; j >= 0; --j) {
    CM Aj;
    Aj.ar = wag[j][0]; Aj.ai = wag[j][1]; Aj.br = wag[j][2]; Aj.bi = wag[j][3];
    Aj.cr = wag[j][4]; Aj.ci = wag[j][5]; Aj.dr = wag[j][6]; Aj.di = wag[j][7];
    E = cmmul(E, Aj);
    cmnorm(E);
  }
  // state vector u = E * [1, 0]^T  (projective; handles a=inf naturally)
  float u0r = E.ar, u0i = E.ai, u1r = E.cr, u1i = E.ci;
  float* Rr = rev ? Br : Ar;
  float* Ri = rev ? Bi : Ai;
#pragma unroll
  for (int q = 0; q < 8; ++q) {
    float dr = dv[q];
    float n0r = dr * u0r + u0i - u1r;  // (dr - i)*u0 - u1
    float n0i = dr * u0i - u0r - u1i;
    u1r = u0r; u1i = u0i; u0r = n0r; u0i = n0i;
    float m = fmaxf(fmaxf(fabsf(u0r), fabsf(u0i)), fmaxf(fabsf(u1r), fabsf(u1i)));
    float sc = 1.f / fmaxf(m, 1e-30f);
    u0r *= sc; u0i *= sc; u1r *= sc; u1i *= sc;
    float den = u1r * u1r + u1i * u1i;
    float arr = (u0r * u1r + u0i * u1i) / den;
    float aii = (u0i * u1r - u0r * u1i) / den;
    int s = sbase + q;
    int n = rev ? (SEQ - 1 - s) : s;
    Rr[b * SEQ + n] = arr;
    Ri[b * SEQ + n] = aii;
  }
}

// ---------------- final (in place on d_out): out += bk_scale*(feats@Wo+bo) ------
__global__ __launch_bounds__(256) void k_final(
    float* __restrict__ outf, const float* __restrict__ v,
    const float* __restrict__ Ar, const float* __restrict__ Ai,
    const float* __restrict__ Br, const float* __restrict__ Bi,
    const float* __restrict__ score, const float* __restrict__ thr,
    const float* __restrict__ Wo, const float* __restrict__ bo,
    const float* __restrict__ bk) {
  int t = blockIdx.x;
  int b = t >> 11;
  float vc = fminf(3.f, fmaxf(-3.f, v[t]));
  float cr = Ar[t] + Br[t] - vc;
  float ci = Ai[t] + Bi[t] + 1.f;
  float den = cr * cr + ci * ci;
  float gr = cr / den, gi = -ci / den;
  bool m = (score[t] >= thr[b]);
  float fr = m ? fminf(10.f, fmaxf(-10.f, gr)) : 0.f;
  float fi = m ? fminf(10.f, fmaxf(-10.f, gi)) : 0.f;
  float bs = bk[0];
  for (int d = threadIdx.x; d < DDIM; d += 256) {
    float o = outf[(size_t)t * DDIM + d] +
              bs * (fr * Wo[d] + fi * Wo[DDIM + d] + bo[d]);
    outf[(size_t)t * DDIM + d] = o;
  }
}

extern "C" void kernel_launch(void* const* d_in, const int* in_sizes, int n_in,
                              void* d_out, int out_size, void* d_ws, size_t ws_size,
                              hipStream_t stream) {
  const float* x  = (const float*)d_in[0];
  const float* Wg = (const float*)d_in[1];
  const float* bg = (const float*)d_in[2];
  const float* W1 = (const float*)d_in[3];
  const float* b1 = (const float*)d_in[4];
  const float* W2 = (const float*)d_in[5];
  const float* b2 = (const float*)d_in[6];
  const float* Wv = (const float*)d_in[7];
  const float* bv = (const float*)d_in[8];
  const float* Wm = (const float*)d_in[9];
  const float* bm = (const float*)d_in[10];
  const float* Wo = (const float*)d_in[11];
  const float* bo = (const float*)d_in[12];
  const float* bk = (const float*)d_in[13];
  float* outf = (float*)d_out;

  unsigned char* w = (unsigned char*)d_ws;
  int*   expert     = (int*)(w + 0);
  float* topp       = (float*)(w + 16384);
  float* score      = (float*)(w + 32768);
  float* v          = (float*)(w + 49152);
  float* Ar         = (float*)(w + 65536);
  float* Ai         = (float*)(w + 81920);
  float* Br         = (float*)(w + 98304);
  float* Bi         = (float*)(w + 114688);
  float* thr        = (float*)(w + 131072);
  int*   meta       = (int*)(w + 131104);
  int*   tiles      = (int*)(w + 131136);
  int*   slot_token = (int*)(w + 131328);            // 5120 ints
  ushort_t* xp      = (ushort_t*)(w + 152064);       // 5120*768  bf16 = 7.9 MB
  ushort_t* h       = (ushort_t*)(w + 8016384);      // 5120*3072 bf16 = 31.5 MB
  ushort_t* Wt      = (ushort_t*)(w + 39473664);     // 8*3072*768 bf16 = 37.7 MB (reused)
  // total ~77.3 MB

  k_gate<<<1024, 256, 0, stream>>>(x, Wg, bg, Wm, bm, expert, topp, score);
  k_thr<<<2, 256, 0, stream>>>(score, thr);
  k_bucket<<<1, 256, 0, stream>>>(expert, meta, tiles, slot_token);
  k_xperm<<<MAXSLOTS, 256, 0, stream>>>(x, slot_token, xp);

  k_wt<<<dim3(12, 48, 8), 256, 0, stream>>>(W1, Wt, 768, 3072);
  k_gemm1<<<dim3(MAXTILES, 24), 256, 0, stream>>>(xp, Wt, b1, meta, tiles, h);

  k_wt<<<dim3(48, 12, 8), 256, 0, stream>>>(W2, Wt, 3072, 768);
  k_gemm2<<<dim3(MAXTILES, 12), 256, 0, stream>>>(h, Wt, b2, topp, meta, tiles,
                                                  slot_token, outf);

  k_vdot<<<1024, 256, 0, stream>>>(outf, Wv, bv, v);
  k_bkscan<<<4, 256, 0, stream>>>(v, Ar, Ai, Br, Bi);
  k_final<<<NTOK, 256, 0, stream>>>(outf, v, Ar, Ai, Br, Bi, score, thr, Wo, bo, bk);
}

// Round 5
// 423.825 us; speedup vs baseline: 4.3236x; 1.0175x over previous
//
#include <hip/hip_runtime.h>

typedef unsigned short ushort_t;
typedef unsigned int uint32;

#define NTOK 4096
#define SEQ 2048
#define DDIM 768
#define HDIM 3072
#define NEXP 8
#define KKEEP 819
#define MTILE 128
#define MAXTILES 40
#define MAXSLOTS 5120

typedef __attribute__((ext_vector_type(8))) short bfrag8;   // 8 bf16 (4 VGPRs)
typedef __attribute__((ext_vector_type(4))) float facc4;    // 4 fp32 acc

__device__ __forceinline__ ushort_t f2bf(float f) {
  uint32 x = __float_as_uint(f);
  uint32 r = (x + 0x7FFFu + ((x >> 16) & 1u)) >> 16;
  return (ushort_t)r;
}
__device__ __forceinline__ float gelu_f(float u) {
  float u3 = u * u * u;
  return 0.5f * u * (1.f + tanhf(0.7978845608028654f * (u + 0.044715f * u3)));
}

// async global->LDS, 16 bytes per lane, LDS dest contiguous in lane order
#define GL2LDS(gp, lp)                                                        \
  __builtin_amdgcn_global_load_lds(                                           \
      (const __attribute__((address_space(1))) void*)(gp),                    \
      (__attribute__((address_space(3))) void*)(lp), 16, 0, 0)

// ---------------- gate: softmax top-1 expert + mask score + v init --------------
__global__ __launch_bounds__(256) void k_gate(
    const float* __restrict__ x, const float* __restrict__ Wg,
    const float* __restrict__ bg, const float* __restrict__ Wm,
    const float* __restrict__ bm, const float* __restrict__ bv,
    int* __restrict__ expert, float* __restrict__ topp,
    float* __restrict__ score, float* __restrict__ v) {
  int tid = threadIdx.x, lane = tid & 63, w = tid >> 6;
  int t = blockIdx.x * 4 + w;
  float g[8];
#pragma unroll
  for (int e = 0; e < 8; ++e) g[e] = 0.f;
  float sm = 0.f;
  for (int d = lane; d < DDIM; d += 64) {
    float xv = x[(size_t)t * DDIM + d];
    float4 w0 = *(const float4*)(Wg + d * 8);
    float4 w1 = *(const float4*)(Wg + d * 8 + 4);
    g[0] += xv * w0.x; g[1] += xv * w0.y; g[2] += xv * w0.z; g[3] += xv * w0.w;
    g[4] += xv * w1.x; g[5] += xv * w1.y; g[6] += xv * w1.z; g[7] += xv * w1.w;
    sm += xv * Wm[d];
  }
#pragma unroll
  for (int e = 0; e < 8; ++e) {
#pragma unroll
    for (int off = 32; off > 0; off >>= 1) g[e] += __shfl_down(g[e], off, 64);
  }
#pragma unroll
  for (int off = 32; off > 0; off >>= 1) sm += __shfl_down(sm, off, 64);
  if (lane == 0) {
    float l[8];
#pragma unroll
    for (int e = 0; e < 8; ++e) l[e] = g[e] + bg[e];
    int am = 0;
    float mx = l[0];
#pragma unroll
    for (int e = 1; e < 8; ++e) {
      if (l[e] > mx) { mx = l[e]; am = e; }  // first-max = jnp.argmax
    }
    float s = 0.f;
#pragma unroll
    for (int e = 0; e < 8; ++e) s += expf(l[e] - mx);
    expert[t] = am;
    topp[t] = 1.f / s;
    float z = sm + bm[0];
    score[t] = 1.f / (1.f + expf(-z));
    v[t] = bv[0];  // init for gemm2's fused vdot atomic accumulation
  }
}

// ---------------- merged: histogram top-K threshold (b<2) + bucket (b==2) -------
__global__ __launch_bounds__(256) void k_thrbucket(
    const float* __restrict__ score, float* __restrict__ thr,
    const int* __restrict__ expert, int* __restrict__ meta,
    int* __restrict__ tiles, int* __restrict__ slot_token) {
  int tid = threadIdx.x;
  if (blockIdx.x < 2) {
    int b = blockIdx.x;
    __shared__ uint32 chist[256];
    __shared__ float vals[2048];
    __shared__ uint32 scnt;
    __shared__ int bstar_s, kprime_s;
    chist[tid] = 0;
    if (tid == 0) scnt = 0;
    __syncthreads();
    for (int i = tid; i < SEQ; i += 256) {
      float s = score[b * SEQ + i];
      int bin = min(255, max(0, (int)(s * 256.f)));
      atomicAdd(&chist[bin], 1u);
    }
    __syncthreads();
    if (tid == 0) {
      int cum = 0;
      for (int j = 255; j >= 0; --j) {
        cum += (int)chist[j];
        if (cum >= KKEEP) {
          bstar_s = j;
          kprime_s = KKEEP - (cum - (int)chist[j]);
          break;
        }
      }
    }
    __syncthreads();
    int bstar = bstar_s, kprime = kprime_s;
    for (int i = tid; i < SEQ; i += 256) {
      float s = score[b * SEQ + i];
      int bin = min(255, max(0, (int)(s * 256.f)));
      if (bin == bstar) vals[atomicAdd(&scnt, 1u)] = s;
    }
    __syncthreads();
    int n = (int)scnt;
    for (int ci = tid; ci < n; ci += 256) {
      float xx = vals[ci];
      int g = 0, eq = 0;
      for (int j = 0; j < n; ++j) {
        g += (vals[j] > xx);
        eq += (vals[j] == xx);
      }
      if (g < kprime && kprime <= g + eq) thr[b] = xx;  // exact K-th largest
    }
  } else {
    __shared__ int cnt[NEXP];
    __shared__ int off[NEXP];
    if (tid < NEXP) cnt[tid] = 0;
    __syncthreads();
    for (int t = tid; t < NTOK; t += 256) atomicAdd(&cnt[expert[t]], 1);
    __syncthreads();
    if (tid == 0) {
      int run = 0, nt = 0;
      for (int e = 0; e < NEXP; ++e) {
        off[e] = run;
        int c = cnt[e];
        int padded = (c + MTILE - 1) / MTILE * MTILE;
        for (int s = 0; s < padded; s += MTILE)
          tiles[nt++] = (e << 16) | (run + s);
        run += padded;
      }
      meta[0] = nt;
      meta[1] = run;
    }
    __syncthreads();
    for (int s = tid; s < MAXSLOTS; s += 256) slot_token[s] = -1;
    __syncthreads();
    for (int t = tid; t < NTOK; t += 256) {
      int p = atomicAdd(&off[expert[t]], 1);
      slot_token[p] = t;
    }
  }
}

// ---------------- merged: x-gather (bx<MAXSLOTS) + W1 transpose -----------------
// wt part: fp32 [e][K][N] -> bf16 [e][N][K], 64x64 tiles, flat grid
__global__ __launch_bounds__(256) void k_prep(
    const float* __restrict__ x, const int* __restrict__ slot_token,
    ushort_t* __restrict__ xp, const float* __restrict__ src,
    ushort_t* __restrict__ dst, int K, int N, int nkb) {
  __shared__ float t[64][65];
  int bx = blockIdx.x;
  int tid = threadIdx.x;
  if (bx < MAXSLOTS) {
    int tok = slot_token[bx];
    for (int d = tid; d < DDIM; d += 256) {
      float vv = (tok >= 0) ? x[(size_t)tok * DDIM + d] : 0.f;
      xp[(size_t)bx * DDIM + d] = f2bf(vv);
    }
    return;
  }
  int bi = bx - MAXSLOTS;
  int per_e = nkb * (N / 64);
  int e = bi / per_e, rem = bi % per_e;
  int k0 = (rem % nkb) * 64, n0 = (rem / nkb) * 64;
  const float* S = src + (size_t)e * K * N;
  ushort_t* D = dst + (size_t)e * N * K;
  int r = tid >> 4, c4 = (tid & 15) * 4;
#pragma unroll
  for (int it = 0; it < 4; ++it) {
    int k = r + it * 16;
    float4 vv = *(const float4*)(S + (size_t)(k0 + k) * N + n0 + c4);
    t[k][c4] = vv.x; t[k][c4 + 1] = vv.y; t[k][c4 + 2] = vv.z; t[k][c4 + 3] = vv.w;
  }
  __syncthreads();
#pragma unroll
  for (int it = 0; it < 4; ++it) {
    int n = r + it * 16;
    ushort4 o;
    o.x = f2bf(t[c4][n]); o.y = f2bf(t[c4 + 1][n]);
    o.z = f2bf(t[c4 + 2][n]); o.w = f2bf(t[c4 + 3][n]);
    *(ushort4*)(D + (size_t)(n0 + n) * K + k0 + c4) = o;
  }
}

// standalone weight transpose (W2), flat grid
__global__ __launch_bounds__(256) void k_wt(const float* __restrict__ src,
                                            ushort_t* __restrict__ dst, int K,
                                            int N, int nkb) {
  __shared__ float t[64][65];
  int bi = blockIdx.x;
  int per_e = nkb * (N / 64);
  int e = bi / per_e, rem = bi % per_e;
  int k0 = (rem % nkb) * 64, n0 = (rem / nkb) * 64;
  const float* S = src + (size_t)e * K * N;
  ushort_t* D = dst + (size_t)e * N * K;
  int tid = threadIdx.x;
  int r = tid >> 4, c4 = (tid & 15) * 4;
#pragma unroll
  for (int it = 0; it < 4; ++it) {
    int k = r + it * 16;
    float4 vv = *(const float4*)(S + (size_t)(k0 + k) * N + n0 + c4);
    t[k][c4] = vv.x; t[k][c4 + 1] = vv.y; t[k][c4 + 2] = vv.z; t[k][c4 + 3] = vv.w;
  }
  __syncthreads();
#pragma unroll
  for (int it = 0; it < 4; ++it) {
    int n = r + it * 16;
    ushort4 o;
    o.x = f2bf(t[c4][n]); o.y = f2bf(t[c4 + 1][n]);
    o.z = f2bf(t[c4 + 2][n]); o.w = f2bf(t[c4 + 3][n]);
    *(ushort4*)(D + (size_t)(n0 + n) * K + k0 + c4) = o;
  }
}

// ---------------- grouped MFMA GEMM layer 1: h = gelu(xp @ W1 + b1) -------------
// LDS chunk-plane layout [kchunk][row][16B]: bank = 4*(row&7) -> 2-way, free.
// GL2LDS dest stays lane-contiguous; the GLOBAL source is permuted instead.
__global__ __launch_bounds__(256) void k_gemm1(
    const ushort_t* __restrict__ xp, const ushort_t* __restrict__ Wt,
    const float* __restrict__ b1, const int* __restrict__ meta,
    const int* __restrict__ tiles, ushort_t* __restrict__ h) {
  __shared__ ushort_t As[128 * 32];
  __shared__ ushort_t Bs[128 * 32];
  if ((int)blockIdx.x >= meta[0]) return;
  int desc = tiles[blockIdx.x];
  int e = desc >> 16, slot0 = desc & 0xFFFF;
  int n0 = blockIdx.y * 128;
  int tid = threadIdx.x;
  int lane = tid & 63, w = tid >> 6;
  int mq = (w & 1) << 6, nq = (w >> 1) << 6;
  int mrow = lane & 15, quad = lane >> 4;
  int rA = tid & 127, cA = (tid >> 7) << 3;  // row, chunk-elem-offset (0/8)
  const ushort_t* Ag = xp + (size_t)slot0 * 768 + (size_t)rA * 768 + cA;
  const ushort_t* Bg = Wt + ((size_t)e * 3072 + n0 + rA) * 768 + cA;
  facc4 acc[4][4];
  facc4 zero = {0.f, 0.f, 0.f, 0.f};
#pragma unroll
  for (int i = 0; i < 4; ++i)
#pragma unroll
    for (int j = 0; j < 4; ++j) acc[i][j] = zero;
  for (int k0 = 0; k0 < 768; k0 += 32) {
    GL2LDS(Ag + k0, As + tid * 8);
    GL2LDS(Ag + k0 + 16, As + (tid + 256) * 8);
    GL2LDS(Bg + k0, Bs + tid * 8);
    GL2LDS(Bg + k0 + 16, Bs + (tid + 256) * 8);
    __syncthreads();
    bfrag8 a[4], b[4];
#pragma unroll
    for (int i = 0; i < 4; ++i)
      a[i] = *(const bfrag8*)(As + (quad << 10) + ((mq + i * 16 + mrow) << 3));
#pragma unroll
    for (int j = 0; j < 4; ++j)
      b[j] = *(const bfrag8*)(Bs + (quad << 10) + ((nq + j * 16 + mrow) << 3));
#pragma unroll
    for (int i = 0; i < 4; ++i)
#pragma unroll
      for (int j = 0; j < 4; ++j)
        acc[i][j] = __builtin_amdgcn_mfma_f32_16x16x32_bf16(a[i], b[j],
                                                            acc[i][j], 0, 0, 0);
    __syncthreads();
  }
  const float* bb = b1 + (size_t)e * 3072 + n0;
#pragma unroll
  for (int i = 0; i < 4; ++i) {
    int mo = mq + i * 16 + (quad << 2);
#pragma unroll
    for (int j = 0; j < 4; ++j) {
      int nc = nq + j * 16 + mrow;
      float bias = bb[nc];
#pragma unroll
      for (int r = 0; r < 4; ++r) {
        float val = gelu_f(acc[i][j][r] + bias);
        h[(size_t)(slot0 + mo + r) * 3072 + n0 + nc] = f2bf(val);
      }
    }
  }
}

// ---------------- grouped MFMA GEMM layer 2 + fused vdot ------------------------
// out = topp*(h @ W2 + b2); v[tok] += sum_n out*Wv (atomic, v pre-init to bv)
__global__ __launch_bounds__(256) void k_gemm2(
    const ushort_t* __restrict__ h, const ushort_t* __restrict__ Wt,
    const float* __restrict__ b2, const float* __restrict__ topp,
    const float* __restrict__ Wv, const int* __restrict__ meta,
    const int* __restrict__ tiles, const int* __restrict__ slot_token,
    float* __restrict__ outf, float* __restrict__ v) {
  __shared__ ushort_t As[128 * 32];
  __shared__ ushort_t Bs[64 * 32];
  if ((int)blockIdx.x >= meta[0]) return;
  int desc = tiles[blockIdx.x];
  int e = desc >> 16, slot0 = desc & 0xFFFF;
  int n0 = blockIdx.y * 64;  // 12 n-blocks
  int tid = threadIdx.x;
  int lane = tid & 63, w = tid >> 6;
  int mq = (w & 1) << 6;   // 0 / 64
  int nq = (w >> 1) << 5;  // 0 / 32
  int mrow = lane & 15, quad = lane >> 4;
  int rA = tid & 127, cA = (tid >> 7) << 3;
  int rB = tid & 63, cB = (tid >> 6) << 3;
  const ushort_t* Ag = h + ((size_t)(slot0 + rA)) * 3072 + cA;
  const ushort_t* Bg = Wt + ((size_t)e * 768 + n0 + rB) * 3072 + cB;
  facc4 acc[4][2];
  facc4 zero = {0.f, 0.f, 0.f, 0.f};
#pragma unroll
  for (int i = 0; i < 4; ++i)
#pragma unroll
    for (int j = 0; j < 2; ++j) acc[i][j] = zero;
  for (int k0 = 0; k0 < 3072; k0 += 32) {
    GL2LDS(Ag + k0, As + tid * 8);
    GL2LDS(Ag + k0 + 16, As + (tid + 256) * 8);
    GL2LDS(Bg + k0, Bs + tid * 8);
    __syncthreads();
    bfrag8 a[4], b[2];
#pragma unroll
    for (int i = 0; i < 4; ++i)
      a[i] = *(const bfrag8*)(As + (quad << 10) + ((mq + i * 16 + mrow) << 3));
#pragma unroll
    for (int j = 0; j < 2; ++j)
      b[j] = *(const bfrag8*)(Bs + (quad << 9) + ((nq + j * 16 + mrow) << 3));
#pragma unroll
    for (int i = 0; i < 4; ++i)
#pragma unroll
      for (int j = 0; j < 2; ++j)
        acc[i][j] = __builtin_amdgcn_mfma_f32_16x16x32_bf16(a[i], b[j],
                                                            acc[i][j], 0, 0, 0);
    __syncthreads();
  }
  const float* bb = b2 + (size_t)e * 768 + n0;
  float wv0 = Wv[n0 + nq + mrow];
  float wv1 = Wv[n0 + nq + 16 + mrow];
  float bb0 = bb[nq + mrow], bb1 = bb[nq + 16 + mrow];
#pragma unroll
  for (int i = 0; i < 4; ++i) {
    int mo = mq + i * 16 + (quad << 2);
#pragma unroll
    for (int r = 0; r < 4; ++r) {
      int slot = slot0 + mo + r;
      int tok = slot_token[slot];  // uniform within 16-lane quad segment
      if (tok < 0) continue;
      float tp = topp[tok];
      float f0 = tp * (acc[i][0][r] + bb0);
      float f1 = tp * (acc[i][1][r] + bb1);
      outf[(size_t)tok * 768 + n0 + nq + mrow] = f0;
      outf[(size_t)tok * 768 + n0 + nq + 16 + mrow] = f1;
      float pv = f0 * wv0 + f1 * wv1;
#pragma unroll
      for (int off = 8; off > 0; off >>= 1) pv += __shfl_down(pv, off, 16);
      if (mrow == 0) atomicAdd(&v[tok], pv);
    }
  }
}

// ---------------- BK parallel scan: Mobius matrices, 3-level scan ---------------
struct CM {
  float ar, ai, br, bi, cr, ci, dr, di;  // [[a,b],[c,d]] complex
};
__device__ __forceinline__ CM cmmul(const CM& A, const CM& B) {  // A*B
  CM C;
  C.ar = A.ar * B.ar - A.ai * B.ai + A.br * B.cr - A.bi * B.ci;
  C.ai = A.ar * B.ai + A.ai * B.ar + A.br * B.ci + A.bi * B.cr;
  C.br = A.ar * B.br - A.ai * B.bi + A.br * B.dr - A.bi * B.di;
  C.bi = A.ar * B.bi + A.ai * B.br + A.br * B.di + A.bi * B.dr;
  C.cr = A.cr * B.ar - A.ci * B.ai + A.dr * B.cr - A.di * B.ci;
  C.ci = A.cr * B.ai + A.ci * B.ar + A.dr * B.ci + A.di * B.cr;
  C.dr = A.cr * B.br - A.ci * B.bi + A.dr * B.dr - A.di * B.di;
  C.di = A.cr * B.bi + A.ci * B.br + A.dr * B.di + A.di * B.dr;
  return C;
}
__device__ __forceinline__ void cmnorm(CM& A) {
  float m = fmaxf(fmaxf(fmaxf(fabsf(A.ar), fabsf(A.ai)),
                        fmaxf(fabsf(A.br), fabsf(A.bi))),
                  fmaxf(fmaxf(fabsf(A.cr), fabsf(A.ci)),
                        fmaxf(fabsf(A.dr), fabsf(A.di))));
  float s = 1.0f / fmaxf(m, 1e-30f);
  A.ar *= s; A.ai *= s; A.br *= s; A.bi *= s;
  A.cr *= s; A.ci *= s; A.dr *= s; A.di *= s;
}
__device__ __forceinline__ CM cmshfl_up(const CM& A, int off) {
  CM B;
  B.ar = __shfl_up(A.ar, off, 64); B.ai = __shfl_up(A.ai, off, 64);
  B.br = __shfl_up(A.br, off, 64); B.bi = __shfl_up(A.bi, off, 64);
  B.cr = __shfl_up(A.cr, off, 64); B.ci = __shfl_up(A.ci, off, 64);
  B.dr = __shfl_up(A.dr, off, 64); B.di = __shfl_up(A.di, off, 64);
  return B;
}

__global__ __launch_bounds__(256) void k_bkscan(
    const float* __restrict__ v, float* __restrict__ Ar, float* __restrict__ Ai,
    float* __restrict__ Br, float* __restrict__ Bi) {
  int b = blockIdx.x >> 1, rev = blockIdx.x & 1;
  int tid = threadIdx.x, lane = tid & 63, wv = tid >> 6;
  const float* vb = v + b * SEQ;
  float dv[8];
  int sbase = tid * 8;
#pragma unroll
  for (int q = 0; q < 8; ++q) {
    int s = sbase + q;
    int n = rev ? (SEQ - 1 - s) : s;
    dv[q] = fminf(3.f, fmaxf(-3.f, vb[n]));
  }
  CM L;
  L.ar = dv[0]; L.ai = -1.f; L.br = -1.f; L.bi = 0.f;
  L.cr = 1.f; L.ci = 0.f; L.dr = 0.f; L.di = 0.f;
#pragma unroll
  for (int q = 1; q < 8; ++q) {
    float dr = dv[q];
    float nar = dr * L.ar + L.ai - L.cr;
    float nai = dr * L.ai - L.ar - L.ci;
    float nbr = dr * L.br + L.bi - L.dr;
    float nbi = dr * L.bi - L.br - L.di;
    L.cr = L.ar; L.ci = L.ai; L.dr = L.br; L.di = L.bi;
    L.ar = nar; L.ai = nai; L.br = nbr; L.bi = nbi;
  }
  cmnorm(L);
  CM I = L;
#pragma unroll
  for (int off = 1; off < 64; off <<= 1) {
    CM P = cmshfl_up(I, off);
    if (lane >= off) {
      I = cmmul(I, P);
      cmnorm(I);
    }
  }
  __shared__ float wag[4][8];
  if (lane == 63) {
    wag[wv][0] = I.ar; wag[wv][1] = I.ai; wag[wv][2] = I.br; wag[wv][3] = I.bi;
    wag[wv][4] = I.cr; wag[wv][5] = I.ci; wag[wv][6] = I.dr; wag[wv][7] = I.di;
  }
  __syncthreads();
  CM E = cmshfl_up(I, 1);
  if (lane == 0) {
    E.ar = 1.f; E.ai = 0.f; E.br = 0.f; E.bi = 0.f;
    E.cr = 0.f; E.ci = 0.f; E.dr = 1.f; E.di = 0.f;
  }
  for (int j = wv - 1; j >= 0; --j) {
    CM Aj;
    Aj.ar = wag[j][0]; Aj.ai = wag[j][1]; Aj.br = wag[j][2]; Aj.bi = wag[j][3];
    Aj.cr = wag[j][4]; Aj.ci = wag[j][5]; Aj.dr = wag[j][6]; Aj.di = wag[j][7];
    E = cmmul(E, Aj);
    cmnorm(E);
  }
  float u0r = E.ar, u0i = E.ai, u1r = E.cr, u1i = E.ci;
  float* Rr = rev ? Br : Ar;
  float* Ri = rev ? Bi : Ai;
#pragma unroll
  for (int q = 0; q < 8; ++q) {
    float dr = dv[q];
    float n0r = dr * u0r + u0i - u1r;
    float n0i = dr * u0i - u0r - u1i;
    u1r = u0r; u1i = u0i; u0r = n0r; u0i = n0i;
    float m = fmaxf(fmaxf(fabsf(u0r), fabsf(u0i)), fmaxf(fabsf(u1r), fabsf(u1i)));
    float sc = 1.f / fmaxf(m, 1e-30f);
    u0r *= sc; u0i *= sc; u1r *= sc; u1i *= sc;
    float den = u1r * u1r + u1i * u1i;
    float arr = (u0r * u1r + u0i * u1i) / den;
    float aii = (u0i * u1r - u0r * u1i) / den;
    int s = sbase + q;
    int n = rev ? (SEQ - 1 - s) : s;
    Rr[b * SEQ + n] = arr;
    Ri[b * SEQ + n] = aii;
  }
}

// ---------------- final (in place on d_out): out += bk_scale*(feats@Wo+bo) ------
__global__ __launch_bounds__(256) void k_final(
    float* __restrict__ outf, const float* __restrict__ v,
    const float* __restrict__ Ar, const float* __restrict__ Ai,
    const float* __restrict__ Br, const float* __restrict__ Bi,
    const float* __restrict__ score, const float* __restrict__ thr,
    const float* __restrict__ Wo, const float* __restrict__ bo,
    const float* __restrict__ bk) {
  int t = blockIdx.x;
  int b = t >> 11;
  float vc = fminf(3.f, fmaxf(-3.f, v[t]));
  float cr = Ar[t] + Br[t] - vc;
  float ci = Ai[t] + Bi[t] + 1.f;
  float den = cr * cr + ci * ci;
  float gr = cr / den, gi = -ci / den;
  bool m = (score[t] >= thr[b]);
  float fr = m ? fminf(10.f, fmaxf(-10.f, gr)) : 0.f;
  float fi = m ? fminf(10.f, fmaxf(-10.f, gi)) : 0.f;
  float bs = bk[0];
  for (int d = threadIdx.x; d < DDIM; d += 256) {
    float o = outf[(size_t)t * DDIM + d] +
              bs * (fr * Wo[d] + fi * Wo[DDIM + d] + bo[d]);
    outf[(size_t)t * DDIM + d] = o;
  }
}

extern "C" void kernel_launch(void* const* d_in, const int* in_sizes, int n_in,
                              void* d_out, int out_size, void* d_ws, size_t ws_size,
                              hipStream_t stream) {
  const float* x  = (const float*)d_in[0];
  const float* Wg = (const float*)d_in[1];
  const float* bg = (const float*)d_in[2];
  const float* W1 = (const float*)d_in[3];
  const float* b1 = (const float*)d_in[4];
  const float* W2 = (const float*)d_in[5];
  const float* b2 = (const float*)d_in[6];
  const float* Wv = (const float*)d_in[7];
  const float* bv = (const float*)d_in[8];
  const float* Wm = (const float*)d_in[9];
  const float* bm = (const float*)d_in[10];
  const float* Wo = (const float*)d_in[11];
  const float* bo = (const float*)d_in[12];
  const float* bk = (const float*)d_in[13];
  float* outf = (float*)d_out;

  unsigned char* w = (unsigned char*)d_ws;
  int*   expert     = (int*)(w + 0);
  float* topp       = (float*)(w + 16384);
  float* score      = (float*)(w + 32768);
  float* v          = (float*)(w + 49152);
  float* Ar         = (float*)(w + 65536);
  float* Ai         = (float*)(w + 81920);
  float* Br         = (float*)(w + 98304);
  float* Bi         = (float*)(w + 114688);
  float* thr        = (float*)(w + 131072);
  int*   meta       = (int*)(w + 131104);
  int*   tiles      = (int*)(w + 131136);
  int*   slot_token = (int*)(w + 131328);            // 5120 ints
  ushort_t* xp      = (ushort_t*)(w + 152064);       // 5120*768  bf16 = 7.9 MB
  ushort_t* h       = (ushort_t*)(w + 8016384);      // 5120*3072 bf16 = 31.5 MB
  ushort_t* Wt      = (ushort_t*)(w + 39473664);     // 8*3072*768 bf16 = 37.7 MB (reused)
  // total ~77.3 MB

  k_gate<<<1024, 256, 0, stream>>>(x, Wg, bg, Wm, bm, bv, expert, topp, score, v);
  k_thrbucket<<<3, 256, 0, stream>>>(score, thr, expert, meta, tiles, slot_token);

  // xperm (5120 blocks) + W1 transpose (8*12*48=4608 blocks) in one launch
  k_prep<<<MAXSLOTS + 4608, 256, 0, stream>>>(x, slot_token, xp, W1, Wt, 768,
                                              3072, 12);
  k_gemm1<<<dim3(MAXTILES, 24), 256, 0, stream>>>(xp, Wt, b1, meta, tiles, h);

  k_wt<<<4608, 256, 0, stream>>>(W2, Wt, 3072, 768, 48);
  k_gemm2<<<dim3(MAXTILES, 12), 256, 0, stream>>>(h, Wt, b2, topp, Wv, meta,
                                                  tiles, slot_token, outf, v);

  k_bkscan<<<4, 256, 0, stream>>>(v, Ar, Ai, Br, Bi);
  k_final<<<NTOK, 256, 0, stream>>>(outf, v, Ar, Ai, Br, Bi, score, thr, Wo, bo, bk);
}